// Round 8
// baseline (449.533 us; speedup 1.0000x reference)
//
#include <hip/hip_runtime.h>
#include <math.h>

#define NNODES 50000
#define NEDGES 800000

typedef _Float16 f16;
typedef __attribute__((ext_vector_type(2))) _Float16 f16x2;
typedef __attribute__((ext_vector_type(4))) _Float16 f16x4;
typedef __attribute__((ext_vector_type(8))) _Float16 f16x8;
typedef __attribute__((ext_vector_type(4))) float f32x4;

__device__ __forceinline__ float leaky02(float v) { return v > 0.f ? v : 0.2f * v; }

// ---------------- init: zero counts + fp16 weight transposes ----------------

__global__ __launch_bounds__(256) void init_kernel(int* __restrict__ counts,
                                                   const float* __restrict__ W1,
                                                   const float* __restrict__ W2,
                                                   const float* __restrict__ W3,
                                                   f16* __restrict__ WT1,
                                                   f16* __restrict__ WT2,
                                                   f16* __restrict__ WT3) {
  int gid = blockIdx.x * 256 + threadIdx.x;
  int stride = gridDim.x * 256;
  for (int i = gid; i < NNODES / 4; i += stride) ((int4*)counts)[i] = make_int4(0, 0, 0, 0);
  for (int i = gid; i < 32768; i += stride) {       // W1: K=256, D=128
    int d = i >> 8, k = i & 255;
    WT1[i] = (f16)W1[k * 128 + d];
  }
  for (int i = gid; i < 16384; i += stride) {       // W2: K=128, D=128
    int d = i >> 7, k = i & 127;
    WT2[i] = (f16)W2[k * 128 + d];
  }
  for (int i = gid; i < 8192; i += stride) {        // W3: K=128, D=64
    int d = i >> 7, k = i & 127;
    WT3[i] = (f16)W3[k * 64 + d];
  }
}

// ---------------- CSR build ----------------

__global__ __launch_bounds__(256) void hist_kernel(const int* __restrict__ dst,
                                                   int* __restrict__ counts, int ne) {
  int i = blockIdx.x * blockDim.x + threadIdx.x;
  if (i < ne) atomicAdd(&counts[dst[i]], 1);
}

__global__ __launch_bounds__(1024) void scan_all_kernel(const int* __restrict__ counts,
                                                        int* __restrict__ offsets,
                                                        int* __restrict__ cursor, int n) {
  __shared__ int ws[16];
  __shared__ int tileTot;
  int tid = threadIdx.x;
  int lane = tid & 63, wid = tid >> 6;
  int carry = 0;
  for (int base = 0; base < n; base += 4096) {
    int i0 = base + tid * 4;
    int4 c = make_int4(0, 0, 0, 0);
    if (i0 + 3 < n) c = *(const int4*)&counts[i0];
    else {
      if (i0 + 0 < n) c.x = counts[i0 + 0];
      if (i0 + 1 < n) c.y = counts[i0 + 1];
      if (i0 + 2 < n) c.z = counts[i0 + 2];
      if (i0 + 3 < n) c.w = counts[i0 + 3];
    }
    int s = c.x + c.y + c.z + c.w;
    int incl = s;
    #pragma unroll
    for (int o = 1; o < 64; o <<= 1) {
      int u = __shfl_up(incl, o, 64);
      if (lane >= o) incl += u;
    }
    if (lane == 63) ws[wid] = incl;
    __syncthreads();
    if (tid == 0) {
      int a = 0;
      #pragma unroll
      for (int w = 0; w < 16; ++w) { int t = ws[w]; ws[w] = a; a += t; }
      tileTot = a;
    }
    __syncthreads();
    int run = carry + ws[wid] + (incl - s);
    if (i0 + 0 < n) { offsets[i0 + 0] = run; cursor[i0 + 0] = run; run += c.x; }
    if (i0 + 1 < n) { offsets[i0 + 1] = run; cursor[i0 + 1] = run; run += c.y; }
    if (i0 + 2 < n) { offsets[i0 + 2] = run; cursor[i0 + 2] = run; run += c.z; }
    if (i0 + 3 < n) { offsets[i0 + 3] = run; cursor[i0 + 3] = run; run += c.w; }
    carry += tileTot;
    __syncthreads();
  }
  if (tid == 0) offsets[n] = carry;
}

// writes (src, ew-bits) pairs directly in CSR order — no perm indirection later
__global__ __launch_bounds__(256) void scatter_kernel(const int* __restrict__ dst,
                                                      const int* __restrict__ src,
                                                      const float* __restrict__ ew,
                                                      int* __restrict__ cursor,
                                                      int2* __restrict__ edgeSW, int ne) {
  int i = blockIdx.x * blockDim.x + threadIdx.x;
  if (i < ne) {
    int pos = atomicAdd(&cursor[dst[i]], 1);
    edgeSW[pos] = make_int2(src[i], __float_as_int(ew[i]));
  }
}

// ---------------- L1: fp32-A MFMA GEMM + fused attn-logit epilogue ----------
// BM=64, BK=64, BN=128. 4 waves 2x2; 16x16x32 f16 MFMA, fp32 accumulate.

__global__ __launch_bounds__(256) void gemm1_kernel(const float* __restrict__ A,
                                                    const f16* __restrict__ BT,
                                                    f16* __restrict__ C,
                                                    const float* __restrict__ a_src,
                                                    const float* __restrict__ a_dst,
                                                    float* __restrict__ als,
                                                    float* __restrict__ ald,
                                                    int M, int K) {
  constexpr int BN = 128, WN = 64, MT = 2, NT = 4;
  __shared__ f16 As[64 * 72];
  __shared__ f16 Bs[BN * 72];
  int tid = threadIdx.x;
  int lane = tid & 63, wave = tid >> 6;
  int wm = wave & 1, wn = wave >> 1;
  int row0 = blockIdx.x * 64;
  int quad = lane >> 4, cc = lane & 15;

  f32x4 acc[MT][NT];
  #pragma unroll
  for (int mt = 0; mt < MT; ++mt)
    #pragma unroll
    for (int nt = 0; nt < NT; ++nt)
      acc[mt][nt] = (f32x4){0.f, 0.f, 0.f, 0.f};

  for (int k0 = 0; k0 < K; k0 += 64) {
    __syncthreads();
    #pragma unroll
    for (int i = 0; i < 4; ++i) {
      int r = i * 16 + (tid >> 4);
      int kc = (tid & 15) * 4;
      float4 av = make_float4(0.f, 0.f, 0.f, 0.f);
      if (row0 + r < M) av = *(const float4*)&A[(size_t)(row0 + r) * K + k0 + kc];
      *(f16x4*)&As[r * 72 + kc] = (f16x4){(f16)av.x, (f16)av.y, (f16)av.z, (f16)av.w};
    }
    #pragma unroll
    for (int i = 0; i < 4; ++i) {
      int d = i * 32 + (tid >> 3);
      int kc = (tid & 7) * 8;
      *(f16x8*)&Bs[d * 72 + kc] = *(const f16x8*)&BT[(size_t)d * K + k0 + kc];
    }
    __syncthreads();
    #pragma unroll
    for (int ki = 0; ki < 2; ++ki) {
      f16x8 a[MT], b[NT];
      #pragma unroll
      for (int mt = 0; mt < MT; ++mt)
        a[mt] = *(const f16x8*)&As[(wm * 32 + mt * 16 + cc) * 72 + ki * 32 + quad * 8];
      #pragma unroll
      for (int nt = 0; nt < NT; ++nt)
        b[nt] = *(const f16x8*)&Bs[(wn * WN + nt * 16 + cc) * 72 + ki * 32 + quad * 8];
      #pragma unroll
      for (int mt = 0; mt < MT; ++mt)
        #pragma unroll
        for (int nt = 0; nt < NT; ++nt)
          acc[mt][nt] = __builtin_amdgcn_mfma_f32_16x16x32_f16(a[mt], b[nt], acc[mt][nt], 0, 0, 0);
    }
  }

  float asv[NT], adv[NT];
  #pragma unroll
  for (int nt = 0; nt < NT; ++nt) {
    int ch = wn * WN + nt * 16 + cc;
    asv[nt] = a_src[ch];
    adv[nt] = a_dst[ch];
  }

  #pragma unroll
  for (int mt = 0; mt < MT; ++mt)
    #pragma unroll
    for (int v = 0; v < 4; ++v) {
      int row = row0 + wm * 32 + mt * 16 + quad * 4 + v;
      if (row < M) {
        #pragma unroll
        for (int nt = 0; nt < NT; ++nt)
          C[(size_t)row * BN + wn * WN + nt * 16 + cc] = (f16)acc[mt][nt][v];
      }
      float s0 = acc[mt][0][v] * asv[0] + acc[mt][1][v] * asv[1];
      float s1 = acc[mt][2][v] * asv[2] + acc[mt][3][v] * asv[3];
      float d0 = acc[mt][0][v] * adv[0] + acc[mt][1][v] * adv[1];
      float d1 = acc[mt][2][v] * adv[2] + acc[mt][3][v] * adv[3];
      #pragma unroll
      for (int o = 1; o < 16; o <<= 1) {
        s0 += __shfl_xor(s0, o);
        s1 += __shfl_xor(s1, o);
        d0 += __shfl_xor(d0, o);
        d1 += __shfl_xor(d1, o);
      }
      if (cc == 0 && row < M) {
        *(float2*)&als[row * 4 + 2 * wn] = make_float2(s0, s1);
        *(float2*)&ald[row * 4 + 2 * wn] = make_float2(d0, d1);
      }
    }
}

// ---------------- fused: aggregate(prev layer) -> LDS A-tile -> GEMM --------
// Block covers 64 nodes. Phase 1: 8 half-waves aggregate 8 nodes each from the
// 128-ch gather table into the LDS A-tile (bias+relu applied). Phase 2: K=128
// MFMA GEMM against the register-staged weight tile. Epilogue: fp16 C + fused
// attention logits (H=4 shuffle-reduce, H=1 LDS combine). Weight loads are
// issued BEFORE aggregation so their latency hides under the gather.

template<int BN, int H>
__global__ __launch_bounds__(256) void fused_agg_gemm_kernel(
    const f16* __restrict__ hin,
    const float* __restrict__ alsI, const float* __restrict__ aldI,
    const int* __restrict__ offsets, const int2* __restrict__ edgeSW,
    const float* __restrict__ biasI,
    const f16* __restrict__ BT,
    const float* __restrict__ a_src, const float* __restrict__ a_dst,
    f16* __restrict__ C, float* __restrict__ alsO, float* __restrict__ aldO,
    int M) {
  constexpr int ASTR = 136;
  constexpr int WN = BN / 2, NT = WN / 16, MT = 2;
  constexpr int NB = BN * 16 / 256;     // weight chunks per thread (8 or 4)
  __shared__ f16 As[64 * ASTR];
  __shared__ f16 Bs[BN * ASTR];
  __shared__ float redS[2][2][32], redD[2][2][32];
  int tid = threadIdx.x;
  int r0 = blockIdx.x * 64;

  // stage weights into registers (loads in flight during aggregation)
  f16x8 breg[NB];
  #pragma unroll
  for (int c = 0; c < NB; ++c) {
    int id = tid + 256 * c;
    int row = id >> 4, kc = (id & 15) * 8;
    breg[c] = *(const f16x8*)&BT[row * 128 + kc];
  }

  // phase 1: aggregate 64 nodes (half-wave per node, 8 nodes each)
  int hw = tid >> 5, hl = tid & 31;
  for (int i = 0; i < 8; ++i) {
    int nl = hw * 8 + i;
    int node = r0 + nl;
    if (node >= M) {
      *(f16x4*)&As[nl * ASTR + 4 * hl] = (f16x4){0, 0, 0, 0};
      continue;
    }
    int start = offsets[node], end = offsets[node + 1];
    int deg = end - start;
    float4 aldv = *(const float4*)&aldI[node * 4];

    int s0 = 0; float wgt0 = 0.f;
    float v0 = 0.f, v1 = 0.f, v2 = 0.f, v3 = 0.f;
    float m0 = -INFINITY, m1 = -INFINITY, m2 = -INFINITY, m3 = -INFINITY;
    if (hl < deg) {
      int2 e = edgeSW[start + hl];
      s0 = e.x;
      wgt0 = __int_as_float(e.y);
      float4 a4 = *(const float4*)&alsI[s0 * 4];
      v0 = leaky02(a4.x + aldv.x); m0 = v0;
      v1 = leaky02(a4.y + aldv.y); m1 = v1;
      v2 = leaky02(a4.z + aldv.z); m2 = v2;
      v3 = leaky02(a4.w + aldv.w); m3 = v3;
    }
    for (int j = start + 32 + hl; j < end; j += 32) {   // rare deg > 32
      int2 e = edgeSW[j];
      float4 a4 = *(const float4*)&alsI[e.x * 4];
      m0 = fmaxf(m0, leaky02(a4.x + aldv.x));
      m1 = fmaxf(m1, leaky02(a4.y + aldv.y));
      m2 = fmaxf(m2, leaky02(a4.z + aldv.z));
      m3 = fmaxf(m3, leaky02(a4.w + aldv.w));
    }
    #pragma unroll
    for (int o = 16; o > 0; o >>= 1) {
      m0 = fmaxf(m0, __shfl_xor(m0, o, 32));
      m1 = fmaxf(m1, __shfl_xor(m1, o, 32));
      m2 = fmaxf(m2, __shfl_xor(m2, o, 32));
      m3 = fmaxf(m3, __shfl_xor(m3, o, 32));
    }
    float w0 = 0.f, w1 = 0.f, w2 = 0.f, w3 = 0.f;
    if (hl < deg) {
      w0 = __expf(v0 - m0) * wgt0;
      w1 = __expf(v1 - m1) * wgt0;
      w2 = __expf(v2 - m2) * wgt0;
      w3 = __expf(v3 - m3) * wgt0;
    }
    int head = hl >> 3;
    float aX = 0.f, aY = 0.f, aZ = 0.f, aW = 0.f, dd = 0.f;
    int cn = deg < 32 ? deg : 32;
    int j = 0;
    for (; j + 8 <= cn; j += 8) {
      f16x4 hv[8]; float wj[8];
      #pragma unroll
      for (int u = 0; u < 8; ++u) {
        int sj = __shfl(s0, j + u, 32);
        float t0 = __shfl(w0, j + u, 32), t1 = __shfl(w1, j + u, 32);
        float t2 = __shfl(w2, j + u, 32), t3 = __shfl(w3, j + u, 32);
        wj[u] = head == 0 ? t0 : head == 1 ? t1 : head == 2 ? t2 : t3;
        hv[u] = *(const f16x4*)&hin[(size_t)sj * 128 + 4 * hl];
      }
      #pragma unroll
      for (int u = 0; u < 8; ++u) {
        dd += wj[u];
        aX += wj[u] * (float)hv[u][0];
        aY += wj[u] * (float)hv[u][1];
        aZ += wj[u] * (float)hv[u][2];
        aW += wj[u] * (float)hv[u][3];
      }
    }
    for (; j < cn; ++j) {
      int sj = __shfl(s0, j, 32);
      float t0 = __shfl(w0, j, 32), t1 = __shfl(w1, j, 32);
      float t2 = __shfl(w2, j, 32), t3 = __shfl(w3, j, 32);
      float wa = head == 0 ? t0 : head == 1 ? t1 : head == 2 ? t2 : t3;
      f16x4 hv = *(const f16x4*)&hin[(size_t)sj * 128 + 4 * hl];
      dd += wa;
      aX += wa * (float)hv[0];
      aY += wa * (float)hv[1];
      aZ += wa * (float)hv[2];
      aW += wa * (float)hv[3];
    }
    for (int base = start + 32; base < end; base += 32) {  // rare deg > 32
      int cnt = end - base; if (cnt > 32) cnt = 32;
      int st = 0; float u0 = 0.f, u1 = 0.f, u2 = 0.f, u3 = 0.f;
      if (hl < cnt) {
        int2 e = edgeSW[base + hl];
        st = e.x;
        float wg = __int_as_float(e.y);
        float4 a4 = *(const float4*)&alsI[st * 4];
        u0 = __expf(leaky02(a4.x + aldv.x) - m0) * wg;
        u1 = __expf(leaky02(a4.y + aldv.y) - m1) * wg;
        u2 = __expf(leaky02(a4.z + aldv.z) - m2) * wg;
        u3 = __expf(leaky02(a4.w + aldv.w) - m3) * wg;
      }
      for (int jj = 0; jj < cnt; ++jj) {
        int sj = __shfl(st, jj, 32);
        float t0 = __shfl(u0, jj, 32), t1 = __shfl(u1, jj, 32);
        float t2 = __shfl(u2, jj, 32), t3 = __shfl(u3, jj, 32);
        float wa = head == 0 ? t0 : head == 1 ? t1 : head == 2 ? t2 : t3;
        f16x4 hv = *(const f16x4*)&hin[(size_t)sj * 128 + 4 * hl];
        dd += wa;
        aX += wa * (float)hv[0];
        aY += wa * (float)hv[1];
        aZ += wa * (float)hv[2];
        aW += wa * (float)hv[3];
      }
    }
    float inv = 1.f / (dd + 1e-16f);
    float4 bv = *(const float4*)&biasI[4 * hl];
    float oX = fmaxf(aX * inv + bv.x, 0.f);   // relu always on for layers 1,2
    float oY = fmaxf(aY * inv + bv.y, 0.f);
    float oZ = fmaxf(aZ * inv + bv.z, 0.f);
    float oW = fmaxf(aW * inv + bv.w, 0.f);
    *(f16x4*)&As[nl * ASTR + 4 * hl] = (f16x4){(f16)oX, (f16)oY, (f16)oZ, (f16)oW};
  }

  // commit weights to LDS
  #pragma unroll
  for (int c = 0; c < NB; ++c) {
    int id = tid + 256 * c;
    int row = id >> 4, kc = (id & 15) * 8;
    *(f16x8*)&Bs[row * ASTR + kc] = breg[c];
  }
  __syncthreads();

  // phase 2: GEMM from LDS (K=128)
  int lane = tid & 63, wave = tid >> 6;
  int wm = wave & 1, wn = wave >> 1;
  int quad = lane >> 4, cc = lane & 15;
  f32x4 acc[MT][NT];
  #pragma unroll
  for (int mt = 0; mt < MT; ++mt)
    #pragma unroll
    for (int nt = 0; nt < NT; ++nt)
      acc[mt][nt] = (f32x4){0.f, 0.f, 0.f, 0.f};
  #pragma unroll
  for (int ki = 0; ki < 4; ++ki) {
    f16x8 a[MT], b[NT];
    #pragma unroll
    for (int mt = 0; mt < MT; ++mt)
      a[mt] = *(const f16x8*)&As[(wm * 32 + mt * 16 + cc) * ASTR + ki * 32 + quad * 8];
    #pragma unroll
    for (int nt = 0; nt < NT; ++nt)
      b[nt] = *(const f16x8*)&Bs[(wn * WN + nt * 16 + cc) * ASTR + ki * 32 + quad * 8];
    #pragma unroll
    for (int mt = 0; mt < MT; ++mt)
      #pragma unroll
      for (int nt = 0; nt < NT; ++nt)
        acc[mt][nt] = __builtin_amdgcn_mfma_f32_16x16x32_f16(a[mt], b[nt], acc[mt][nt], 0, 0, 0);
  }

  // epilogue: C + attention logits
  float asv[NT], adv[NT];
  #pragma unroll
  for (int nt = 0; nt < NT; ++nt) {
    int ch = wn * WN + nt * 16 + cc;
    asv[nt] = a_src[ch];
    adv[nt] = a_dst[ch];
  }
  #pragma unroll
  for (int mt = 0; mt < MT; ++mt)
    #pragma unroll
    for (int v = 0; v < 4; ++v) {
      int row = r0 + wm * 32 + mt * 16 + quad * 4 + v;
      if (row < M) {
        #pragma unroll
        for (int nt = 0; nt < NT; ++nt)
          C[(size_t)row * BN + wn * WN + nt * 16 + cc] = (f16)acc[mt][nt][v];
      }
      if constexpr (H == 4) {
        float s0 = acc[mt][0][v] * asv[0] + acc[mt][1][v] * asv[1];
        float s1 = acc[mt][2][v] * asv[2] + acc[mt][3][v] * asv[3];
        float d0 = acc[mt][0][v] * adv[0] + acc[mt][1][v] * adv[1];
        float d1 = acc[mt][2][v] * adv[2] + acc[mt][3][v] * adv[3];
        #pragma unroll
        for (int o = 1; o < 16; o <<= 1) {
          s0 += __shfl_xor(s0, o);
          s1 += __shfl_xor(s1, o);
          d0 += __shfl_xor(d0, o);
          d1 += __shfl_xor(d1, o);
        }
        if (cc == 0 && row < M) {
          *(float2*)&alsO[row * 4 + 2 * wn] = make_float2(s0, s1);
          *(float2*)&aldO[row * 4 + 2 * wn] = make_float2(d0, d1);
        }
      } else {
        float s0 = acc[mt][0][v] * asv[0] + acc[mt][1][v] * asv[1];
        float d0 = acc[mt][0][v] * adv[0] + acc[mt][1][v] * adv[1];
        #pragma unroll
        for (int o = 1; o < 16; o <<= 1) {
          s0 += __shfl_xor(s0, o);
          d0 += __shfl_xor(d0, o);
        }
        int r = mt * 16 + quad * 4 + v;
        if (cc == 0) { redS[wm][wn][r] = s0; redD[wm][wn][r] = d0; }
      }
    }
  if constexpr (H == 1) {
    __syncthreads();
    #pragma unroll
    for (int mt = 0; mt < MT; ++mt)
      #pragma unroll
      for (int v = 0; v < 4; ++v) {
        int row = r0 + wm * 32 + mt * 16 + quad * 4 + v;
        int r = mt * 16 + quad * 4 + v;
        if (wn == 0 && cc == 0 && row < M) {
          alsO[row] = redS[wm][0][r] + redS[wm][1][r];
          aldO[row] = redD[wm][0][r] + redD[wm][1][r];
        }
      }
  }
}

// ---------------- final aggregation (H=1, 64 ch), fp32 output ---------------

__global__ __launch_bounds__(256) void aggregate1_kernel(const f16* __restrict__ h16,
                                                         const float* __restrict__ als,
                                                         const float* __restrict__ ald,
                                                         const int* __restrict__ offsets,
                                                         const int2* __restrict__ edgeSW,
                                                         const float* __restrict__ bias,
                                                         float* __restrict__ out, int n_nodes) {
  int node = blockIdx.x * 8 + (threadIdx.x >> 5);
  int hl = threadIdx.x & 31;
  if (node >= n_nodes) return;
  int start = offsets[node], end = offsets[node + 1];
  int deg = end - start;

  float ald0 = ald[node];
  int s0 = 0; float wgt0 = 0.f, v0 = 0.f, m0 = -INFINITY;
  if (hl < deg) {
    int2 e = edgeSW[start + hl];
    s0 = e.x;
    wgt0 = __int_as_float(e.y);
    v0 = leaky02(als[s0] + ald0);
    m0 = v0;
  }
  for (int j = start + 32 + hl; j < end; j += 32) {
    int2 e = edgeSW[j];
    m0 = fmaxf(m0, leaky02(als[e.x] + ald0));
  }
  #pragma unroll
  for (int o = 16; o > 0; o >>= 1) m0 = fmaxf(m0, __shfl_xor(m0, o, 32));

  float w0 = (hl < deg) ? __expf(v0 - m0) * wgt0 : 0.f;

  float aX = 0.f, aY = 0.f, dd = 0.f;
  int cn = deg < 32 ? deg : 32;
  int j = 0;
  for (; j + 8 <= cn; j += 8) {
    f16x2 hv[8]; float wv[8];
    #pragma unroll
    for (int u = 0; u < 8; ++u) {
      int sj = __shfl(s0, j + u, 32);
      wv[u] = __shfl(w0, j + u, 32);
      hv[u] = *(const f16x2*)&h16[(size_t)sj * 64 + 2 * hl];
    }
    #pragma unroll
    for (int u = 0; u < 8; ++u) {
      dd += wv[u];
      aX += wv[u] * (float)hv[u][0];
      aY += wv[u] * (float)hv[u][1];
    }
  }
  for (; j < cn; ++j) {
    int sj = __shfl(s0, j, 32);
    float wj = __shfl(w0, j, 32);
    f16x2 hv = *(const f16x2*)&h16[(size_t)sj * 64 + 2 * hl];
    dd += wj;
    aX += wj * (float)hv[0];
    aY += wj * (float)hv[1];
  }
  for (int base = start + 32; base < end; base += 32) {
    int cnt = end - base; if (cnt > 32) cnt = 32;
    int st = 0; float u0 = 0.f;
    if (hl < cnt) {
      int2 e = edgeSW[base + hl];
      st = e.x;
      u0 = __expf(leaky02(als[st] + ald0) - m0) * __int_as_float(e.y);
    }
    for (int jj = 0; jj < cnt; ++jj) {
      int sj = __shfl(st, jj, 32);
      float wj = __shfl(u0, jj, 32);
      f16x2 hv = *(const f16x2*)&h16[(size_t)sj * 64 + 2 * hl];
      dd += wj;
      aX += wj * (float)hv[0];
      aY += wj * (float)hv[1];
    }
  }

  float inv = 1.f / (dd + 1e-16f);
  float2 bv = *(const float2*)&bias[2 * hl];
  *(float2*)&out[(size_t)node * 64 + 2 * hl] = make_float2(aX * inv + bv.x, aY * inv + bv.y);
}

// ---------------- launch ----------------

extern "C" void kernel_launch(void* const* d_in, const int* in_sizes, int n_in,
                              void* d_out, int out_size, void* d_ws, size_t ws_size,
                              hipStream_t stream) {
  const int N = NNODES, E = NEDGES;
  const float* x   = (const float*)d_in[0];
  const int*   ei  = (const int*)d_in[1];
  const float* ew  = (const float*)d_in[2];
  const float* W1  = (const float*)d_in[3];
  const float* as1 = (const float*)d_in[4];
  const float* ad1 = (const float*)d_in[5];
  const float* b1  = (const float*)d_in[6];
  const float* W2  = (const float*)d_in[7];
  const float* as2 = (const float*)d_in[8];
  const float* ad2 = (const float*)d_in[9];
  const float* b2  = (const float*)d_in[10];
  const float* W3  = (const float*)d_in[11];
  const float* as3 = (const float*)d_in[12];
  const float* ad3 = (const float*)d_in[13];
  const float* b3  = (const float*)d_in[14];
  const int* src = ei;
  const int* dst = ei + E;

  uint8_t* p = (uint8_t*)d_ws;
  auto carve = [&](size_t bytes) {
    void* r = (void*)p;
    p += (bytes + 255) & ~(size_t)255;
    return r;
  };
  int*   counts  = (int*)carve((size_t)N * 4);
  int*   offsets = (int*)carve((size_t)(N + 1) * 4);
  int*   cursor  = (int*)carve((size_t)N * 4);
  int2*  edgeSW  = (int2*)carve((size_t)E * 8);
  float* als1    = (float*)carve((size_t)N * 4 * 4);
  float* ald1    = (float*)carve((size_t)N * 4 * 4);
  float* als2    = (float*)carve((size_t)N * 4 * 4);
  float* ald2    = (float*)carve((size_t)N * 4 * 4);
  float* als3    = (float*)carve((size_t)N * 4);
  float* ald3    = (float*)carve((size_t)N * 4);
  f16*   hA16    = (f16*)carve((size_t)N * 128 * 2);
  f16*   hB16    = (f16*)carve((size_t)N * 128 * 2);
  f16*   hC16    = (f16*)carve((size_t)N * 64 * 2);
  f16*   WT1     = (f16*)carve((size_t)256 * 128 * 2);
  f16*   WT2     = (f16*)carve((size_t)128 * 128 * 2);
  f16*   WT3     = (f16*)carve((size_t)128 * 64 * 2);

  init_kernel<<<128, 256, 0, stream>>>(counts, W1, W2, W3, WT1, WT2, WT3);
  hist_kernel<<<(E + 255) / 256, 256, 0, stream>>>(dst, counts, E);
  scan_all_kernel<<<1, 1024, 0, stream>>>(counts, offsets, cursor, N);
  scatter_kernel<<<(E + 255) / 256, 256, 0, stream>>>(dst, src, ew, cursor, edgeSW, E);

  int gemmGrid = (N + 63) / 64;

  // L1 linear (+ logits)
  gemm1_kernel<<<gemmGrid, 256, 0, stream>>>(x, WT1, hA16, as1, ad1, als1, ald1, N, 256);
  // agg L1 + L2 linear (+ logits)
  fused_agg_gemm_kernel<128, 4><<<gemmGrid, 256, 0, stream>>>(
      hA16, als1, ald1, offsets, edgeSW, b1, WT2, as2, ad2, hB16, als2, ald2, N);
  // agg L2 + L3 linear (+ logits)
  fused_agg_gemm_kernel<64, 1><<<gemmGrid, 256, 0, stream>>>(
      hB16, als2, ald2, offsets, edgeSW, b2, WT3, as3, ad3, hC16, als3, ald3, N);
  // final aggregation
  aggregate1_kernel<<<(N + 7) / 8, 256, 0, stream>>>(hC16, als3, ald3, offsets, edgeSW,
                                                     b3, (float*)d_out, N);
}

// Round 9
// 391.707 us; speedup vs baseline: 1.1476x; 1.1476x over previous
//
#include <hip/hip_runtime.h>
#include <math.h>

#define NNODES 50000
#define NEDGES 800000

typedef _Float16 f16;
typedef __attribute__((ext_vector_type(2))) _Float16 f16x2;
typedef __attribute__((ext_vector_type(4))) _Float16 f16x4;
typedef __attribute__((ext_vector_type(8))) _Float16 f16x8;
typedef __attribute__((ext_vector_type(4))) float f32x4;

__device__ __forceinline__ float leaky02(float v) { return v > 0.f ? v : 0.2f * v; }

// ---------------- init: zero counts + fp16 weight transposes ----------------

__global__ __launch_bounds__(256) void init_kernel(int* __restrict__ counts,
                                                   const float* __restrict__ W1,
                                                   const float* __restrict__ W2,
                                                   const float* __restrict__ W3,
                                                   f16* __restrict__ WT1,
                                                   f16* __restrict__ WT2,
                                                   f16* __restrict__ WT3) {
  int gid = blockIdx.x * 256 + threadIdx.x;
  int stride = gridDim.x * 256;
  for (int i = gid; i < NNODES / 4; i += stride) ((int4*)counts)[i] = make_int4(0, 0, 0, 0);
  for (int i = gid; i < 32768; i += stride) {       // W1: K=256, D=128
    int d = i >> 8, k = i & 255;
    WT1[i] = (f16)W1[k * 128 + d];
  }
  for (int i = gid; i < 16384; i += stride) {       // W2: K=128, D=128
    int d = i >> 7, k = i & 127;
    WT2[i] = (f16)W2[k * 128 + d];
  }
  for (int i = gid; i < 8192; i += stride) {        // W3: K=128, D=64
    int d = i >> 7, k = i & 127;
    WT3[i] = (f16)W3[k * 64 + d];
  }
}

// ---------------- CSR build ----------------

__global__ __launch_bounds__(256) void hist_kernel(const int* __restrict__ dst,
                                                   int* __restrict__ counts, int ne) {
  int i = blockIdx.x * blockDim.x + threadIdx.x;
  if (i < ne) atomicAdd(&counts[dst[i]], 1);
}

__global__ __launch_bounds__(1024) void scan_all_kernel(const int* __restrict__ counts,
                                                        int* __restrict__ offsets,
                                                        int* __restrict__ cursor, int n) {
  __shared__ int ws[16];
  __shared__ int tileTot;
  int tid = threadIdx.x;
  int lane = tid & 63, wid = tid >> 6;
  int carry = 0;
  for (int base = 0; base < n; base += 4096) {
    int i0 = base + tid * 4;
    int4 c = make_int4(0, 0, 0, 0);
    if (i0 + 3 < n) c = *(const int4*)&counts[i0];
    else {
      if (i0 + 0 < n) c.x = counts[i0 + 0];
      if (i0 + 1 < n) c.y = counts[i0 + 1];
      if (i0 + 2 < n) c.z = counts[i0 + 2];
      if (i0 + 3 < n) c.w = counts[i0 + 3];
    }
    int s = c.x + c.y + c.z + c.w;
    int incl = s;
    #pragma unroll
    for (int o = 1; o < 64; o <<= 1) {
      int u = __shfl_up(incl, o, 64);
      if (lane >= o) incl += u;
    }
    if (lane == 63) ws[wid] = incl;
    __syncthreads();
    if (tid == 0) {
      int a = 0;
      #pragma unroll
      for (int w = 0; w < 16; ++w) { int t = ws[w]; ws[w] = a; a += t; }
      tileTot = a;
    }
    __syncthreads();
    int run = carry + ws[wid] + (incl - s);
    if (i0 + 0 < n) { offsets[i0 + 0] = run; cursor[i0 + 0] = run; run += c.x; }
    if (i0 + 1 < n) { offsets[i0 + 1] = run; cursor[i0 + 1] = run; run += c.y; }
    if (i0 + 2 < n) { offsets[i0 + 2] = run; cursor[i0 + 2] = run; run += c.z; }
    if (i0 + 3 < n) { offsets[i0 + 3] = run; cursor[i0 + 3] = run; run += c.w; }
    carry += tileTot;
    __syncthreads();
  }
  if (tid == 0) offsets[n] = carry;
}

// writes (src, ew-bits) pairs directly in CSR order — no perm indirection later
__global__ __launch_bounds__(256) void scatter_kernel(const int* __restrict__ dst,
                                                      const int* __restrict__ src,
                                                      const float* __restrict__ ew,
                                                      int* __restrict__ cursor,
                                                      int2* __restrict__ edgeSW, int ne) {
  int i = blockIdx.x * blockDim.x + threadIdx.x;
  if (i < ne) {
    int pos = atomicAdd(&cursor[dst[i]], 1);
    edgeSW[pos] = make_int2(src[i], __float_as_int(ew[i]));
  }
}

// ---------------- fp16 MFMA GEMM + fused attention-logit epilogue -----------
// BM=64, BK=64, BN == D. 4 waves 2x2; 16x16x32 f16 MFMA, fp32 accumulate.

template<typename AT, int BN, int H>
__global__ __launch_bounds__(256) void gemm_mfma_kernel(const AT* __restrict__ A,
                                                        const f16* __restrict__ BT,
                                                        f16* __restrict__ C,
                                                        const float* __restrict__ a_src,
                                                        const float* __restrict__ a_dst,
                                                        float* __restrict__ als,
                                                        float* __restrict__ ald,
                                                        int M, int K) {
  constexpr int BM = 64;
  constexpr int WN = BN / 2;
  constexpr int MT = 2, NT = WN / 16;
  __shared__ f16 As[BM * 72];
  __shared__ f16 Bs[BN * 72];
  __shared__ float redS[2][2][32], redD[2][2][32];   // only used when H==1
  int tid = threadIdx.x;
  int lane = tid & 63, wave = tid >> 6;
  int wm = wave & 1, wn = wave >> 1;
  int row0 = blockIdx.x * BM;
  int quad = lane >> 4, cc = lane & 15;

  f32x4 acc[MT][NT];
  #pragma unroll
  for (int mt = 0; mt < MT; ++mt)
    #pragma unroll
    for (int nt = 0; nt < NT; ++nt)
      acc[mt][nt] = (f32x4){0.f, 0.f, 0.f, 0.f};

  for (int k0 = 0; k0 < K; k0 += 64) {
    __syncthreads();
    if constexpr (sizeof(AT) == 4) {
      #pragma unroll
      for (int i = 0; i < 4; ++i) {
        int r = i * 16 + (tid >> 4);
        int kc = (tid & 15) * 4;
        float4 av = make_float4(0.f, 0.f, 0.f, 0.f);
        if (row0 + r < M) av = *(const float4*)&A[(size_t)(row0 + r) * K + k0 + kc];
        *(f16x4*)&As[r * 72 + kc] = (f16x4){(f16)av.x, (f16)av.y, (f16)av.z, (f16)av.w};
      }
    } else {
      #pragma unroll
      for (int i = 0; i < 2; ++i) {
        int r = i * 32 + (tid >> 3);
        int kc = (tid & 7) * 8;
        f16x8 hv = {0, 0, 0, 0, 0, 0, 0, 0};
        if (row0 + r < M) hv = *(const f16x8*)&A[(size_t)(row0 + r) * K + k0 + kc];
        *(f16x8*)&As[r * 72 + kc] = hv;
      }
    }
    #pragma unroll
    for (int i = 0; i < BN / 32; ++i) {
      int d = i * 32 + (tid >> 3);
      int kc = (tid & 7) * 8;
      *(f16x8*)&Bs[d * 72 + kc] = *(const f16x8*)&BT[(size_t)d * K + k0 + kc];
    }
    __syncthreads();
    #pragma unroll
    for (int ki = 0; ki < 2; ++ki) {
      f16x8 a[MT], b[NT];
      #pragma unroll
      for (int mt = 0; mt < MT; ++mt)
        a[mt] = *(const f16x8*)&As[(wm * 32 + mt * 16 + cc) * 72 + ki * 32 + quad * 8];
      #pragma unroll
      for (int nt = 0; nt < NT; ++nt)
        b[nt] = *(const f16x8*)&Bs[(wn * WN + nt * 16 + cc) * 72 + ki * 32 + quad * 8];
      #pragma unroll
      for (int mt = 0; mt < MT; ++mt)
        #pragma unroll
        for (int nt = 0; nt < NT; ++nt)
          acc[mt][nt] = __builtin_amdgcn_mfma_f32_16x16x32_f16(a[mt], b[nt], acc[mt][nt], 0, 0, 0);
    }
  }

  float asv[NT], adv[NT];
  #pragma unroll
  for (int nt = 0; nt < NT; ++nt) {
    int ch = wn * WN + nt * 16 + cc;
    asv[nt] = a_src[ch];
    adv[nt] = a_dst[ch];
  }

  #pragma unroll
  for (int mt = 0; mt < MT; ++mt)
    #pragma unroll
    for (int v = 0; v < 4; ++v) {
      int row = row0 + wm * 32 + mt * 16 + quad * 4 + v;
      if (row < M) {
        #pragma unroll
        for (int nt = 0; nt < NT; ++nt)
          C[(size_t)row * BN + wn * WN + nt * 16 + cc] = (f16)acc[mt][nt][v];
      }
      if constexpr (H == 4) {
        float s0 = acc[mt][0][v] * asv[0] + acc[mt][1][v] * asv[1];
        float s1 = acc[mt][2][v] * asv[2] + acc[mt][3][v] * asv[3];
        float d0 = acc[mt][0][v] * adv[0] + acc[mt][1][v] * adv[1];
        float d1 = acc[mt][2][v] * adv[2] + acc[mt][3][v] * adv[3];
        #pragma unroll
        for (int o = 1; o < 16; o <<= 1) {
          s0 += __shfl_xor(s0, o);
          s1 += __shfl_xor(s1, o);
          d0 += __shfl_xor(d0, o);
          d1 += __shfl_xor(d1, o);
        }
        if (cc == 0 && row < M) {
          *(float2*)&als[row * 4 + 2 * wn] = make_float2(s0, s1);
          *(float2*)&ald[row * 4 + 2 * wn] = make_float2(d0, d1);
        }
      } else {
        float s0 = acc[mt][0][v] * asv[0] + acc[mt][1][v] * asv[1];
        float d0 = acc[mt][0][v] * adv[0] + acc[mt][1][v] * adv[1];
        #pragma unroll
        for (int o = 1; o < 16; o <<= 1) {
          s0 += __shfl_xor(s0, o);
          d0 += __shfl_xor(d0, o);
        }
        int r = mt * 16 + quad * 4 + v;
        if (cc == 0) { redS[wm][wn][r] = s0; redD[wm][wn][r] = d0; }
      }
    }
  if constexpr (H == 1) {
    __syncthreads();
    #pragma unroll
    for (int mt = 0; mt < MT; ++mt)
      #pragma unroll
      for (int v = 0; v < 4; ++v) {
        int row = row0 + wm * 32 + mt * 16 + quad * 4 + v;
        int r = mt * 16 + quad * 4 + v;
        if (wn == 0 && cc == 0 && row < M) {
          als[row] = redS[wm][0][r] + redS[wm][1][r];
          ald[row] = redD[wm][0][r] + redD[wm][1][r];
        }
      }
  }
}

// ---------------- per-dst-node softmax + weighted aggregation ----------------
// Half-wave (32 lanes) per node; edgeSW staging; PREDICATED batch-16 gathers:
// masked lanes carry w=0 / s=0 so no per-edge bounds checks — 16 independent
// h-row loads in flight per batch.

template<bool RELU>
__global__ __launch_bounds__(256) void aggregate4_kernel(const f16* __restrict__ h16,
                                                         const float* __restrict__ als,
                                                         const float* __restrict__ ald,
                                                         const int* __restrict__ offsets,
                                                         const int2* __restrict__ edgeSW,
                                                         const float* __restrict__ bias,
                                                         f16* __restrict__ out, int n_nodes) {
  int node = blockIdx.x * 8 + (threadIdx.x >> 5);
  int hl = threadIdx.x & 31;
  if (node >= n_nodes) return;
  int start = offsets[node], end = offsets[node + 1];
  int deg = end - start;

  float4 aldv = *(const float4*)&ald[node * 4];

  int s0 = 0; float wgt0 = 0.f;
  float v0 = 0.f, v1 = 0.f, v2 = 0.f, v3 = 0.f;
  float m0 = -INFINITY, m1 = -INFINITY, m2 = -INFINITY, m3 = -INFINITY;
  if (hl < deg) {
    int2 e = edgeSW[start + hl];
    s0 = e.x;
    wgt0 = __int_as_float(e.y);
    float4 a4 = *(const float4*)&als[s0 * 4];
    v0 = leaky02(a4.x + aldv.x); m0 = v0;
    v1 = leaky02(a4.y + aldv.y); m1 = v1;
    v2 = leaky02(a4.z + aldv.z); m2 = v2;
    v3 = leaky02(a4.w + aldv.w); m3 = v3;
  }
  for (int j = start + 32 + hl; j < end; j += 32) {   // rare deg > 32
    int2 e = edgeSW[j];
    float4 a4 = *(const float4*)&als[e.x * 4];
    m0 = fmaxf(m0, leaky02(a4.x + aldv.x));
    m1 = fmaxf(m1, leaky02(a4.y + aldv.y));
    m2 = fmaxf(m2, leaky02(a4.z + aldv.z));
    m3 = fmaxf(m3, leaky02(a4.w + aldv.w));
  }
  #pragma unroll
  for (int o = 16; o > 0; o >>= 1) {
    m0 = fmaxf(m0, __shfl_xor(m0, o, 32));
    m1 = fmaxf(m1, __shfl_xor(m1, o, 32));
    m2 = fmaxf(m2, __shfl_xor(m2, o, 32));
    m3 = fmaxf(m3, __shfl_xor(m3, o, 32));
  }
  float w0 = 0.f, w1 = 0.f, w2 = 0.f, w3 = 0.f;
  if (hl < deg) {
    w0 = __expf(v0 - m0) * wgt0;
    w1 = __expf(v1 - m1) * wgt0;
    w2 = __expf(v2 - m2) * wgt0;
    w3 = __expf(v3 - m3) * wgt0;
  }

  int head = hl >> 3;
  float aX = 0.f, aY = 0.f, aZ = 0.f, aW = 0.f, dd = 0.f;
  int cn = deg < 32 ? deg : 32;
  int nb = (cn + 15) >> 4;
  for (int b = 0; b < nb; ++b) {
    int j0 = b * 16;
    f16x4 hv[16]; float wj[16];
    #pragma unroll
    for (int u = 0; u < 16; ++u) {
      int j = j0 + u;
      int sj = __shfl(s0, j, 32);
      float t0 = __shfl(w0, j, 32), t1 = __shfl(w1, j, 32);
      float t2 = __shfl(w2, j, 32), t3 = __shfl(w3, j, 32);
      wj[u] = head == 0 ? t0 : head == 1 ? t1 : head == 2 ? t2 : t3;
      hv[u] = *(const f16x4*)&h16[(size_t)sj * 128 + 4 * hl];
    }
    #pragma unroll
    for (int u = 0; u < 16; ++u) {
      dd += wj[u];
      aX += wj[u] * (float)hv[u][0];
      aY += wj[u] * (float)hv[u][1];
      aZ += wj[u] * (float)hv[u][2];
      aW += wj[u] * (float)hv[u][3];
    }
  }
  for (int base = start + 32; base < end; base += 32) {   // rare deg > 32
    int cnt = end - base; if (cnt > 32) cnt = 32;
    int st = 0; float u0 = 0.f, u1 = 0.f, u2 = 0.f, u3 = 0.f;
    if (hl < cnt) {
      int2 e = edgeSW[base + hl];
      st = e.x;
      float wg = __int_as_float(e.y);
      float4 a4 = *(const float4*)&als[st * 4];
      u0 = __expf(leaky02(a4.x + aldv.x) - m0) * wg;
      u1 = __expf(leaky02(a4.y + aldv.y) - m1) * wg;
      u2 = __expf(leaky02(a4.z + aldv.z) - m2) * wg;
      u3 = __expf(leaky02(a4.w + aldv.w) - m3) * wg;
    }
    for (int jj = 0; jj < cnt; ++jj) {
      int sj = __shfl(st, jj, 32);
      float t0 = __shfl(u0, jj, 32), t1 = __shfl(u1, jj, 32);
      float t2 = __shfl(u2, jj, 32), t3 = __shfl(u3, jj, 32);
      float wa = head == 0 ? t0 : head == 1 ? t1 : head == 2 ? t2 : t3;
      f16x4 hv = *(const f16x4*)&h16[(size_t)sj * 128 + 4 * hl];
      dd += wa;
      aX += wa * (float)hv[0];
      aY += wa * (float)hv[1];
      aZ += wa * (float)hv[2];
      aW += wa * (float)hv[3];
    }
  }

  float inv = 1.f / (dd + 1e-16f);
  float4 bv = *(const float4*)&bias[4 * hl];
  float oX = aX * inv + bv.x, oY = aY * inv + bv.y;
  float oZ = aZ * inv + bv.z, oW = aW * inv + bv.w;
  if (RELU) {
    oX = fmaxf(oX, 0.f); oY = fmaxf(oY, 0.f);
    oZ = fmaxf(oZ, 0.f); oW = fmaxf(oW, 0.f);
  }
  *(f16x4*)&out[(size_t)node * 128 + 4 * hl] = (f16x4){(f16)oX, (f16)oY, (f16)oZ, (f16)oW};
}

// H == 1, C == 64 (layer 3), fp32 output
__global__ __launch_bounds__(256) void aggregate1_kernel(const f16* __restrict__ h16,
                                                         const float* __restrict__ als,
                                                         const float* __restrict__ ald,
                                                         const int* __restrict__ offsets,
                                                         const int2* __restrict__ edgeSW,
                                                         const float* __restrict__ bias,
                                                         float* __restrict__ out, int n_nodes) {
  int node = blockIdx.x * 8 + (threadIdx.x >> 5);
  int hl = threadIdx.x & 31;
  if (node >= n_nodes) return;
  int start = offsets[node], end = offsets[node + 1];
  int deg = end - start;

  float ald0 = ald[node];
  int s0 = 0; float wgt0 = 0.f, v0 = 0.f, m0 = -INFINITY;
  if (hl < deg) {
    int2 e = edgeSW[start + hl];
    s0 = e.x;
    wgt0 = __int_as_float(e.y);
    v0 = leaky02(als[s0] + ald0);
    m0 = v0;
  }
  for (int j = start + 32 + hl; j < end; j += 32) {
    int2 e = edgeSW[j];
    m0 = fmaxf(m0, leaky02(als[e.x] + ald0));
  }
  #pragma unroll
  for (int o = 16; o > 0; o >>= 1) m0 = fmaxf(m0, __shfl_xor(m0, o, 32));

  float w0 = (hl < deg) ? __expf(v0 - m0) * wgt0 : 0.f;

  float aX = 0.f, aY = 0.f, dd = 0.f;
  int cn = deg < 32 ? deg : 32;
  int nb = (cn + 15) >> 4;
  for (int b = 0; b < nb; ++b) {
    int j0 = b * 16;
    f16x2 hv[16]; float wv[16];
    #pragma unroll
    for (int u = 0; u < 16; ++u) {
      int j = j0 + u;
      int sj = __shfl(s0, j, 32);
      wv[u] = __shfl(w0, j, 32);
      hv[u] = *(const f16x2*)&h16[(size_t)sj * 64 + 2 * hl];
    }
    #pragma unroll
    for (int u = 0; u < 16; ++u) {
      dd += wv[u];
      aX += wv[u] * (float)hv[u][0];
      aY += wv[u] * (float)hv[u][1];
    }
  }
  for (int base = start + 32; base < end; base += 32) {
    int cnt = end - base; if (cnt > 32) cnt = 32;
    int st = 0; float u0 = 0.f;
    if (hl < cnt) {
      int2 e = edgeSW[base + hl];
      st = e.x;
      u0 = __expf(leaky02(als[st] + ald0) - m0) * __int_as_float(e.y);
    }
    for (int jj = 0; jj < cnt; ++jj) {
      int sj = __shfl(st, jj, 32);
      float wj = __shfl(u0, jj, 32);
      f16x2 hv = *(const f16x2*)&h16[(size_t)sj * 64 + 2 * hl];
      dd += wj;
      aX += wj * (float)hv[0];
      aY += wj * (float)hv[1];
    }
  }

  float inv = 1.f / (dd + 1e-16f);
  float2 bv = *(const float2*)&bias[2 * hl];
  *(float2*)&out[(size_t)node * 64 + 2 * hl] = make_float2(aX * inv + bv.x, aY * inv + bv.y);
}

// ---------------- launch ----------------

extern "C" void kernel_launch(void* const* d_in, const int* in_sizes, int n_in,
                              void* d_out, int out_size, void* d_ws, size_t ws_size,
                              hipStream_t stream) {
  const int N = NNODES, E = NEDGES;
  const float* x   = (const float*)d_in[0];
  const int*   ei  = (const int*)d_in[1];
  const float* ew  = (const float*)d_in[2];
  const float* W1  = (const float*)d_in[3];
  const float* as1 = (const float*)d_in[4];
  const float* ad1 = (const float*)d_in[5];
  const float* b1  = (const float*)d_in[6];
  const float* W2  = (const float*)d_in[7];
  const float* as2 = (const float*)d_in[8];
  const float* ad2 = (const float*)d_in[9];
  const float* b2  = (const float*)d_in[10];
  const float* W3  = (const float*)d_in[11];
  const float* as3 = (const float*)d_in[12];
  const float* ad3 = (const float*)d_in[13];
  const float* b3  = (const float*)d_in[14];
  const int* src = ei;
  const int* dst = ei + E;

  uint8_t* p = (uint8_t*)d_ws;
  auto carve = [&](size_t bytes) {
    void* r = (void*)p;
    p += (bytes + 255) & ~(size_t)255;
    return r;
  };
  int*   counts  = (int*)carve((size_t)N * 4);
  int*   offsets = (int*)carve((size_t)(N + 1) * 4);
  int*   cursor  = (int*)carve((size_t)N * 4);
  int2*  edgeSW  = (int2*)carve((size_t)E * 8);
  float* als1    = (float*)carve((size_t)N * 4 * 4);
  float* ald1    = (float*)carve((size_t)N * 4 * 4);
  float* als2    = (float*)carve((size_t)N * 4 * 4);
  float* ald2    = (float*)carve((size_t)N * 4 * 4);
  float* als3    = (float*)carve((size_t)N * 4);
  float* ald3    = (float*)carve((size_t)N * 4);
  f16*   hA16    = (f16*)carve((size_t)N * 128 * 2);
  f16*   hB16    = (f16*)carve((size_t)N * 128 * 2);
  f16*   hC16    = (f16*)carve((size_t)N * 64 * 2);
  f16*   WT1     = (f16*)carve((size_t)256 * 128 * 2);
  f16*   WT2     = (f16*)carve((size_t)128 * 128 * 2);
  f16*   WT3     = (f16*)carve((size_t)128 * 64 * 2);

  init_kernel<<<128, 256, 0, stream>>>(counts, W1, W2, W3, WT1, WT2, WT3);
  hist_kernel<<<(E + 255) / 256, 256, 0, stream>>>(dst, counts, E);
  scan_all_kernel<<<1, 1024, 0, stream>>>(counts, offsets, cursor, N);
  scatter_kernel<<<(E + 255) / 256, 256, 0, stream>>>(dst, src, ew, cursor, edgeSW, E);

  int gemmGrid = (N + 63) / 64;
  int aggGrid = (N + 7) / 8;

  // layer 1: [N,256] @ [256,128], H=4 C=32, relu
  gemm_mfma_kernel<float, 128, 4><<<gemmGrid, 256, 0, stream>>>(x, WT1, hA16, as1, ad1,
                                                                als1, ald1, N, 256);
  aggregate4_kernel<true><<<aggGrid, 256, 0, stream>>>(hA16, als1, ald1, offsets, edgeSW,
                                                       b1, hB16, N);
  // layer 2: [N,128] @ [128,128], H=4 C=32, relu
  gemm_mfma_kernel<f16, 128, 4><<<gemmGrid, 256, 0, stream>>>(hB16, WT2, hA16, as2, ad2,
                                                              als2, ald2, N, 128);
  aggregate4_kernel<true><<<aggGrid, 256, 0, stream>>>(hA16, als2, ald2, offsets, edgeSW,
                                                       b2, hB16, N);
  // layer 3: [N,128] @ [128,64], H=1 C=64, no relu, fp32 output
  gemm_mfma_kernel<f16, 64, 1><<<gemmGrid, 256, 0, stream>>>(hB16, WT3, hC16, as3, ad3,
                                                             als3, ald3, N, 128);
  aggregate1_kernel<<<aggGrid, 256, 0, stream>>>(hC16, als3, ald3, offsets, edgeSW,
                                                 b3, (float*)d_out, N);
}

// Round 10
// 344.631 us; speedup vs baseline: 1.3044x; 1.1366x over previous
//
#include <hip/hip_runtime.h>
#include <math.h>

#define NNODES 50000
#define NEDGES 800000
#define SCAN_CHUNK 1024

typedef _Float16 f16;
typedef __attribute__((ext_vector_type(2))) _Float16 f16x2;
typedef __attribute__((ext_vector_type(4))) _Float16 f16x4;
typedef __attribute__((ext_vector_type(8))) _Float16 f16x8;
typedef __attribute__((ext_vector_type(4))) float f32x4;

__device__ __forceinline__ float leaky02(float v) { return v > 0.f ? v : 0.2f * v; }

// ---------------- init: zero counts + fp16 weight transposes ----------------

__global__ __launch_bounds__(256) void init_kernel(int* __restrict__ counts,
                                                   const float* __restrict__ W1,
                                                   const float* __restrict__ W2,
                                                   const float* __restrict__ W3,
                                                   f16* __restrict__ WT1,
                                                   f16* __restrict__ WT2,
                                                   f16* __restrict__ WT3) {
  int gid = blockIdx.x * 256 + threadIdx.x;
  int stride = gridDim.x * 256;
  for (int i = gid; i < NNODES / 4; i += stride) ((int4*)counts)[i] = make_int4(0, 0, 0, 0);
  for (int i = gid; i < 32768; i += stride) {       // W1: K=256, D=128
    int d = i >> 8, k = i & 255;
    WT1[i] = (f16)W1[k * 128 + d];
  }
  for (int i = gid; i < 16384; i += stride) {       // W2: K=128, D=128
    int d = i >> 7, k = i & 127;
    WT2[i] = (f16)W2[k * 128 + d];
  }
  for (int i = gid; i < 8192; i += stride) {        // W3: K=128, D=64
    int d = i >> 7, k = i & 127;
    WT3[i] = (f16)W3[k * 64 + d];
  }
}

// ---------------- CSR build ----------------

__global__ __launch_bounds__(256) void hist_kernel(const int* __restrict__ dst,
                                                   int* __restrict__ counts, int ne) {
  int i = blockIdx.x * blockDim.x + threadIdx.x;
  if (i < ne) atomicAdd(&counts[dst[i]], 1);
}

__global__ __launch_bounds__(256) void scan_reduce_kernel(const int* __restrict__ counts,
                                                          int* __restrict__ blockSums, int n) {
  int tid = threadIdx.x;
  int base = blockIdx.x * SCAN_CHUNK;
  int sum = 0;
  #pragma unroll
  for (int k = 0; k < SCAN_CHUNK / 256; ++k) {
    int i = base + k * 256 + tid;
    if (i < n) sum += counts[i];
  }
  #pragma unroll
  for (int o = 32; o > 0; o >>= 1) sum += __shfl_xor(sum, o);
  __shared__ int ws[4];
  if ((tid & 63) == 0) ws[tid >> 6] = sum;
  __syncthreads();
  if (tid == 0) blockSums[blockIdx.x] = ws[0] + ws[1] + ws[2] + ws[3];
}

__global__ __launch_bounds__(64) void scan_spine_kernel(int* __restrict__ blockSums,
                                                        int* __restrict__ offsets,
                                                        int nb, int n) {
  int tid = threadIdx.x;
  int v = (tid < nb) ? blockSums[tid] : 0;
  int incl = v;
  #pragma unroll
  for (int o = 1; o < 64; o <<= 1) {
    int u = __shfl_up(incl, o, 64);
    if (tid >= o) incl += u;
  }
  if (tid < nb) blockSums[tid] = incl - v;
  if (tid == 63) offsets[n] = incl;
}

__global__ __launch_bounds__(256) void scan_write_kernel(const int* __restrict__ counts,
                                                         const int* __restrict__ blockSums,
                                                         int* __restrict__ offsets,
                                                         int* __restrict__ cursor, int n) {
  int tid = threadIdx.x;
  int base = blockIdx.x * SCAN_CHUNK;
  int i0 = base + tid * 4;
  int4 c = make_int4(0, 0, 0, 0);
  if (i0 + 3 < n) c = *(const int4*)&counts[i0];
  else {
    if (i0 + 0 < n) c.x = counts[i0 + 0];
    if (i0 + 1 < n) c.y = counts[i0 + 1];
    if (i0 + 2 < n) c.z = counts[i0 + 2];
    if (i0 + 3 < n) c.w = counts[i0 + 3];
  }
  int s = c.x + c.y + c.z + c.w;
  int lane = tid & 63, wid = tid >> 6;
  int incl = s;
  #pragma unroll
  for (int o = 1; o < 64; o <<= 1) {
    int u = __shfl_up(incl, o, 64);
    if (lane >= o) incl += u;
  }
  __shared__ int ws[4];
  if (lane == 63) ws[wid] = incl;
  __syncthreads();
  if (tid == 0) {
    int a = 0;
    #pragma unroll
    for (int w = 0; w < 4; ++w) { int t = ws[w]; ws[w] = a; a += t; }
  }
  __syncthreads();
  int run = blockSums[blockIdx.x] + ws[wid] + (incl - s);
  if (i0 + 0 < n) { offsets[i0 + 0] = run; cursor[i0 + 0] = run; run += c.x; }
  if (i0 + 1 < n) { offsets[i0 + 1] = run; cursor[i0 + 1] = run; run += c.y; }
  if (i0 + 2 < n) { offsets[i0 + 2] = run; cursor[i0 + 2] = run; run += c.z; }
  if (i0 + 3 < n) { offsets[i0 + 3] = run; cursor[i0 + 3] = run; run += c.w; }
}

// writes (src, ew-bits) pairs directly in CSR order
__global__ __launch_bounds__(256) void scatter_kernel(const int* __restrict__ dst,
                                                      const int* __restrict__ src,
                                                      const float* __restrict__ ew,
                                                      int* __restrict__ cursor,
                                                      int2* __restrict__ edgeSW, int ne) {
  int i = blockIdx.x * blockDim.x + threadIdx.x;
  if (i < ne) {
    int pos = atomicAdd(&cursor[dst[i]], 1);
    edgeSW[pos] = make_int2(src[i], __float_as_int(ew[i]));
  }
}

// ---------------- fp16 MFMA GEMM + fused attention-logit epilogue -----------

template<typename AT, int BN, int H>
__global__ __launch_bounds__(256) void gemm_mfma_kernel(const AT* __restrict__ A,
                                                        const f16* __restrict__ BT,
                                                        f16* __restrict__ C,
                                                        const float* __restrict__ a_src,
                                                        const float* __restrict__ a_dst,
                                                        float* __restrict__ als,
                                                        float* __restrict__ ald,
                                                        int M, int K) {
  constexpr int BM = 64;
  constexpr int WN = BN / 2;
  constexpr int MT = 2, NT = WN / 16;
  __shared__ f16 As[BM * 72];
  __shared__ f16 Bs[BN * 72];
  __shared__ float redS[2][2][32], redD[2][2][32];   // only used when H==1
  int tid = threadIdx.x;
  int lane = tid & 63, wave = tid >> 6;
  int wm = wave & 1, wn = wave >> 1;
  int row0 = blockIdx.x * BM;
  int quad = lane >> 4, cc = lane & 15;

  f32x4 acc[MT][NT];
  #pragma unroll
  for (int mt = 0; mt < MT; ++mt)
    #pragma unroll
    for (int nt = 0; nt < NT; ++nt)
      acc[mt][nt] = (f32x4){0.f, 0.f, 0.f, 0.f};

  for (int k0 = 0; k0 < K; k0 += 64) {
    __syncthreads();
    if constexpr (sizeof(AT) == 4) {
      #pragma unroll
      for (int i = 0; i < 4; ++i) {
        int r = i * 16 + (tid >> 4);
        int kc = (tid & 15) * 4;
        float4 av = make_float4(0.f, 0.f, 0.f, 0.f);
        if (row0 + r < M) av = *(const float4*)&A[(size_t)(row0 + r) * K + k0 + kc];
        *(f16x4*)&As[r * 72 + kc] = (f16x4){(f16)av.x, (f16)av.y, (f16)av.z, (f16)av.w};
      }
    } else {
      #pragma unroll
      for (int i = 0; i < 2; ++i) {
        int r = i * 32 + (tid >> 3);
        int kc = (tid & 7) * 8;
        f16x8 hv = {0, 0, 0, 0, 0, 0, 0, 0};
        if (row0 + r < M) hv = *(const f16x8*)&A[(size_t)(row0 + r) * K + k0 + kc];
        *(f16x8*)&As[r * 72 + kc] = hv;
      }
    }
    #pragma unroll
    for (int i = 0; i < BN / 32; ++i) {
      int d = i * 32 + (tid >> 3);
      int kc = (tid & 7) * 8;
      *(f16x8*)&Bs[d * 72 + kc] = *(const f16x8*)&BT[(size_t)d * K + k0 + kc];
    }
    __syncthreads();
    #pragma unroll
    for (int ki = 0; ki < 2; ++ki) {
      f16x8 a[MT], b[NT];
      #pragma unroll
      for (int mt = 0; mt < MT; ++mt)
        a[mt] = *(const f16x8*)&As[(wm * 32 + mt * 16 + cc) * 72 + ki * 32 + quad * 8];
      #pragma unroll
      for (int nt = 0; nt < NT; ++nt)
        b[nt] = *(const f16x8*)&Bs[(wn * WN + nt * 16 + cc) * 72 + ki * 32 + quad * 8];
      #pragma unroll
      for (int mt = 0; mt < MT; ++mt)
        #pragma unroll
        for (int nt = 0; nt < NT; ++nt)
          acc[mt][nt] = __builtin_amdgcn_mfma_f32_16x16x32_f16(a[mt], b[nt], acc[mt][nt], 0, 0, 0);
    }
  }

  float asv[NT], adv[NT];
  #pragma unroll
  for (int nt = 0; nt < NT; ++nt) {
    int ch = wn * WN + nt * 16 + cc;
    asv[nt] = a_src[ch];
    adv[nt] = a_dst[ch];
  }

  #pragma unroll
  for (int mt = 0; mt < MT; ++mt)
    #pragma unroll
    for (int v = 0; v < 4; ++v) {
      int row = row0 + wm * 32 + mt * 16 + quad * 4 + v;
      if (row < M) {
        #pragma unroll
        for (int nt = 0; nt < NT; ++nt)
          C[(size_t)row * BN + wn * WN + nt * 16 + cc] = (f16)acc[mt][nt][v];
      }
      if constexpr (H == 4) {
        float s0 = acc[mt][0][v] * asv[0] + acc[mt][1][v] * asv[1];
        float s1 = acc[mt][2][v] * asv[2] + acc[mt][3][v] * asv[3];
        float d0 = acc[mt][0][v] * adv[0] + acc[mt][1][v] * adv[1];
        float d1 = acc[mt][2][v] * adv[2] + acc[mt][3][v] * adv[3];
        #pragma unroll
        for (int o = 1; o < 16; o <<= 1) {
          s0 += __shfl_xor(s0, o);
          s1 += __shfl_xor(s1, o);
          d0 += __shfl_xor(d0, o);
          d1 += __shfl_xor(d1, o);
        }
        if (cc == 0 && row < M) {
          *(float2*)&als[row * 4 + 2 * wn] = make_float2(s0, s1);
          *(float2*)&ald[row * 4 + 2 * wn] = make_float2(d0, d1);
        }
      } else {
        float s0 = acc[mt][0][v] * asv[0] + acc[mt][1][v] * asv[1];
        float d0 = acc[mt][0][v] * adv[0] + acc[mt][1][v] * adv[1];
        #pragma unroll
        for (int o = 1; o < 16; o <<= 1) {
          s0 += __shfl_xor(s0, o);
          d0 += __shfl_xor(d0, o);
        }
        int r = mt * 16 + quad * 4 + v;
        if (cc == 0) { redS[wm][wn][r] = s0; redD[wm][wn][r] = d0; }
      }
    }
  if constexpr (H == 1) {
    __syncthreads();
    #pragma unroll
    for (int mt = 0; mt < MT; ++mt)
      #pragma unroll
      for (int v = 0; v < 4; ++v) {
        int row = row0 + wm * 32 + mt * 16 + quad * 4 + v;
        int r = mt * 16 + quad * 4 + v;
        if (wn == 0 && cc == 0 && row < M) {
          als[row] = redS[wm][0][r] + redS[wm][1][r];
          ald[row] = redD[wm][0][r] + redD[wm][1][r];
        }
      }
  }
}

// ---------------- per-dst-node softmax + weighted aggregation ----------------
// Half-wave per node. Staging lanes compute per-edge (s, w[4]) ONCE and park
// them in bank-padded LDS; after one __syncthreads the inner loop is just
// 2 ds_read (broadcast) + 1 independent gather + FMAs per edge — no
// shuffle/select chain. Batch-16 predicated gathers keep 16 loads in flight.

template<bool RELU>
__global__ __launch_bounds__(256) void aggregate4_kernel(const f16* __restrict__ h16,
                                                         const float* __restrict__ als,
                                                         const float* __restrict__ ald,
                                                         const int* __restrict__ offsets,
                                                         const int2* __restrict__ edgeSW,
                                                         const float* __restrict__ bias,
                                                         f16* __restrict__ out, int n_nodes) {
  __shared__ int   swS[8][33];
  __shared__ float swW[8][4][33];
  int hw = threadIdx.x >> 5;
  int hl = threadIdx.x & 31;
  int node = blockIdx.x * 8 + hw;
  bool valid = node < n_nodes;
  int nodeC = valid ? node : n_nodes - 1;
  int start = offsets[nodeC], end = offsets[nodeC + 1];
  int deg = valid ? end - start : 0;

  float4 aldv = *(const float4*)&ald[nodeC * 4];

  int s0 = 0; float wgt0 = 0.f;
  float v0 = 0.f, v1 = 0.f, v2 = 0.f, v3 = 0.f;
  float m0 = -INFINITY, m1 = -INFINITY, m2 = -INFINITY, m3 = -INFINITY;
  if (hl < deg) {
    int2 e = edgeSW[start + hl];
    s0 = e.x;
    wgt0 = __int_as_float(e.y);
    float4 a4 = *(const float4*)&als[s0 * 4];
    v0 = leaky02(a4.x + aldv.x); m0 = v0;
    v1 = leaky02(a4.y + aldv.y); m1 = v1;
    v2 = leaky02(a4.z + aldv.z); m2 = v2;
    v3 = leaky02(a4.w + aldv.w); m3 = v3;
  }
  for (int j = start + 32 + hl; j < end; j += 32) {   // rare deg > 32
    int2 e = edgeSW[j];
    float4 a4 = *(const float4*)&als[e.x * 4];
    m0 = fmaxf(m0, leaky02(a4.x + aldv.x));
    m1 = fmaxf(m1, leaky02(a4.y + aldv.y));
    m2 = fmaxf(m2, leaky02(a4.z + aldv.z));
    m3 = fmaxf(m3, leaky02(a4.w + aldv.w));
  }
  #pragma unroll
  for (int o = 16; o > 0; o >>= 1) {
    m0 = fmaxf(m0, __shfl_xor(m0, o, 32));
    m1 = fmaxf(m1, __shfl_xor(m1, o, 32));
    m2 = fmaxf(m2, __shfl_xor(m2, o, 32));
    m3 = fmaxf(m3, __shfl_xor(m3, o, 32));
  }
  float w0 = 0.f, w1 = 0.f, w2 = 0.f, w3 = 0.f;
  if (hl < deg) {
    w0 = __expf(v0 - m0) * wgt0;
    w1 = __expf(v1 - m1) * wgt0;
    w2 = __expf(v2 - m2) * wgt0;
    w3 = __expf(v3 - m3) * wgt0;
  }
  swS[hw][hl] = s0;
  swW[hw][0][hl] = w0;
  swW[hw][1][hl] = w1;
  swW[hw][2][hl] = w2;
  swW[hw][3][hl] = w3;
  __syncthreads();

  int head = hl >> 3;
  float aX = 0.f, aY = 0.f, aZ = 0.f, aW = 0.f, dd = 0.f;
  int cn = deg < 32 ? deg : 32;
  int nb = (cn + 15) >> 4;
  for (int b = 0; b < nb; ++b) {
    int j0 = b * 16;
    f16x4 hv[16]; float wj[16];
    #pragma unroll
    for (int u = 0; u < 16; ++u) {
      int j = j0 + u;
      int sj = swS[hw][j];
      wj[u] = swW[hw][head][j];
      hv[u] = *(const f16x4*)&h16[(size_t)sj * 128 + 4 * hl];
    }
    #pragma unroll
    for (int u = 0; u < 16; ++u) {
      dd += wj[u];
      aX += wj[u] * (float)hv[u][0];
      aY += wj[u] * (float)hv[u][1];
      aZ += wj[u] * (float)hv[u][2];
      aW += wj[u] * (float)hv[u][3];
    }
  }
  for (int base = start + 32; base < end; base += 32) {   // rare deg > 32
    int cnt = end - base; if (cnt > 32) cnt = 32;
    int st = 0; float u0 = 0.f, u1 = 0.f, u2 = 0.f, u3 = 0.f;
    if (hl < cnt) {
      int2 e = edgeSW[base + hl];
      st = e.x;
      float wg = __int_as_float(e.y);
      float4 a4 = *(const float4*)&als[st * 4];
      u0 = __expf(leaky02(a4.x + aldv.x) - m0) * wg;
      u1 = __expf(leaky02(a4.y + aldv.y) - m1) * wg;
      u2 = __expf(leaky02(a4.z + aldv.z) - m2) * wg;
      u3 = __expf(leaky02(a4.w + aldv.w) - m3) * wg;
    }
    for (int jj = 0; jj < cnt; ++jj) {
      int sj = __shfl(st, jj, 32);
      float t0 = __shfl(u0, jj, 32), t1 = __shfl(u1, jj, 32);
      float t2 = __shfl(u2, jj, 32), t3 = __shfl(u3, jj, 32);
      float wa = head == 0 ? t0 : head == 1 ? t1 : head == 2 ? t2 : t3;
      f16x4 hv = *(const f16x4*)&h16[(size_t)sj * 128 + 4 * hl];
      dd += wa;
      aX += wa * (float)hv[0];
      aY += wa * (float)hv[1];
      aZ += wa * (float)hv[2];
      aW += wa * (float)hv[3];
    }
  }

  if (valid) {
    float inv = 1.f / (dd + 1e-16f);
    float4 bv = *(const float4*)&bias[4 * hl];
    float oX = aX * inv + bv.x, oY = aY * inv + bv.y;
    float oZ = aZ * inv + bv.z, oW = aW * inv + bv.w;
    if (RELU) {
      oX = fmaxf(oX, 0.f); oY = fmaxf(oY, 0.f);
      oZ = fmaxf(oZ, 0.f); oW = fmaxf(oW, 0.f);
    }
    *(f16x4*)&out[(size_t)node * 128 + 4 * hl] = (f16x4){(f16)oX, (f16)oY, (f16)oZ, (f16)oW};
  }
}

// H == 1, C == 64 (layer 3), fp32 output
__global__ __launch_bounds__(256) void aggregate1_kernel(const f16* __restrict__ h16,
                                                         const float* __restrict__ als,
                                                         const float* __restrict__ ald,
                                                         const int* __restrict__ offsets,
                                                         const int2* __restrict__ edgeSW,
                                                         const float* __restrict__ bias,
                                                         float* __restrict__ out, int n_nodes) {
  __shared__ int   s1s[8][33];
  __shared__ float w1s[8][33];
  int hw = threadIdx.x >> 5;
  int hl = threadIdx.x & 31;
  int node = blockIdx.x * 8 + hw;
  bool valid = node < n_nodes;
  int nodeC = valid ? node : n_nodes - 1;
  int start = offsets[nodeC], end = offsets[nodeC + 1];
  int deg = valid ? end - start : 0;

  float ald0 = ald[nodeC];
  int s0 = 0; float wgt0 = 0.f, v0 = 0.f, m0 = -INFINITY;
  if (hl < deg) {
    int2 e = edgeSW[start + hl];
    s0 = e.x;
    wgt0 = __int_as_float(e.y);
    v0 = leaky02(als[s0] + ald0);
    m0 = v0;
  }
  for (int j = start + 32 + hl; j < end; j += 32) {
    int2 e = edgeSW[j];
    m0 = fmaxf(m0, leaky02(als[e.x] + ald0));
  }
  #pragma unroll
  for (int o = 16; o > 0; o >>= 1) m0 = fmaxf(m0, __shfl_xor(m0, o, 32));

  float w0 = (hl < deg) ? __expf(v0 - m0) * wgt0 : 0.f;
  s1s[hw][hl] = s0;
  w1s[hw][hl] = w0;
  __syncthreads();

  float aX = 0.f, aY = 0.f, dd = 0.f;
  int cn = deg < 32 ? deg : 32;
  int nb = (cn + 15) >> 4;
  for (int b = 0; b < nb; ++b) {
    int j0 = b * 16;
    f16x2 hv[16]; float wv[16];
    #pragma unroll
    for (int u = 0; u < 16; ++u) {
      int j = j0 + u;
      int sj = s1s[hw][j];
      wv[u] = w1s[hw][j];
      hv[u] = *(const f16x2*)&h16[(size_t)sj * 64 + 2 * hl];
    }
    #pragma unroll
    for (int u = 0; u < 16; ++u) {
      dd += wv[u];
      aX += wv[u] * (float)hv[u][0];
      aY += wv[u] * (float)hv[u][1];
    }
  }
  for (int base = start + 32; base < end; base += 32) {
    int cnt = end - base; if (cnt > 32) cnt = 32;
    int st = 0; float u0 = 0.f;
    if (hl < cnt) {
      int2 e = edgeSW[base + hl];
      st = e.x;
      u0 = __expf(leaky02(als[st] + ald0) - m0) * __int_as_float(e.y);
    }
    for (int jj = 0; jj < cnt; ++jj) {
      int sj = __shfl(st, jj, 32);
      float wj = __shfl(u0, jj, 32);
      f16x2 hv = *(const f16x2*)&h16[(size_t)sj * 64 + 2 * hl];
      dd += wj;
      aX += wj * (float)hv[0];
      aY += wj * (float)hv[1];
    }
  }

  if (valid) {
    float inv = 1.f / (dd + 1e-16f);
    float2 bv = *(const float2*)&bias[2 * hl];
    *(float2*)&out[(size_t)node * 64 + 2 * hl] = make_float2(aX * inv + bv.x, aY * inv + bv.y);
  }
}

// ---------------- launch ----------------

extern "C" void kernel_launch(void* const* d_in, const int* in_sizes, int n_in,
                              void* d_out, int out_size, void* d_ws, size_t ws_size,
                              hipStream_t stream) {
  const int N = NNODES, E = NEDGES;
  const float* x   = (const float*)d_in[0];
  const int*   ei  = (const int*)d_in[1];
  const float* ew  = (const float*)d_in[2];
  const float* W1  = (const float*)d_in[3];
  const float* as1 = (const float*)d_in[4];
  const float* ad1 = (const float*)d_in[5];
  const float* b1  = (const float*)d_in[6];
  const float* W2  = (const float*)d_in[7];
  const float* as2 = (const float*)d_in[8];
  const float* ad2 = (const float*)d_in[9];
  const float* b2  = (const float*)d_in[10];
  const float* W3  = (const float*)d_in[11];
  const float* as3 = (const float*)d_in[12];
  const float* ad3 = (const float*)d_in[13];
  const float* b3  = (const float*)d_in[14];
  const int* src = ei;
  const int* dst = ei + E;

  uint8_t* p = (uint8_t*)d_ws;
  auto carve = [&](size_t bytes) {
    void* r = (void*)p;
    p += (bytes + 255) & ~(size_t)255;
    return r;
  };
  int*   counts  = (int*)carve((size_t)N * 4);
  int*   offsets = (int*)carve((size_t)(N + 1) * 4);
  int*   cursor  = (int*)carve((size_t)N * 4);
  int2*  edgeSW  = (int2*)carve((size_t)E * 8);
  int*   bsums   = (int*)carve((size_t)256 * 4);
  float* als1    = (float*)carve((size_t)N * 4 * 4);
  float* ald1    = (float*)carve((size_t)N * 4 * 4);
  float* als2    = (float*)carve((size_t)N * 4 * 4);
  float* ald2    = (float*)carve((size_t)N * 4 * 4);
  float* als3    = (float*)carve((size_t)N * 4);
  float* ald3    = (float*)carve((size_t)N * 4);
  f16*   hA16    = (f16*)carve((size_t)N * 128 * 2);
  f16*   hB16    = (f16*)carve((size_t)N * 128 * 2);
  f16*   hC16    = (f16*)carve((size_t)N * 64 * 2);
  f16*   WT1     = (f16*)carve((size_t)256 * 128 * 2);
  f16*   WT2     = (f16*)carve((size_t)128 * 128 * 2);
  f16*   WT3     = (f16*)carve((size_t)128 * 64 * 2);

  int nb = (N + SCAN_CHUNK - 1) / SCAN_CHUNK;   // 49 <= 64
  init_kernel<<<128, 256, 0, stream>>>(counts, W1, W2, W3, WT1, WT2, WT3);
  hist_kernel<<<(E + 255) / 256, 256, 0, stream>>>(dst, counts, E);
  scan_reduce_kernel<<<nb, 256, 0, stream>>>(counts, bsums, N);
  scan_spine_kernel<<<1, 64, 0, stream>>>(bsums, offsets, nb, N);
  scan_write_kernel<<<nb, 256, 0, stream>>>(counts, bsums, offsets, cursor, N);
  scatter_kernel<<<(E + 255) / 256, 256, 0, stream>>>(dst, src, ew, cursor, edgeSW, E);

  int gemmGrid = (N + 63) / 64;
  int aggGrid = (N + 7) / 8;

  // layer 1: [N,256] @ [256,128], H=4 C=32, relu
  gemm_mfma_kernel<float, 128, 4><<<gemmGrid, 256, 0, stream>>>(x, WT1, hA16, as1, ad1,
                                                                als1, ald1, N, 256);
  aggregate4_kernel<true><<<aggGrid, 256, 0, stream>>>(hA16, als1, ald1, offsets, edgeSW,
                                                       b1, hB16, N);
  // layer 2: [N,128] @ [128,128], H=4 C=32, relu
  gemm_mfma_kernel<f16, 128, 4><<<gemmGrid, 256, 0, stream>>>(hB16, WT2, hA16, as2, ad2,
                                                              als2, ald2, N, 128);
  aggregate4_kernel<true><<<aggGrid, 256, 0, stream>>>(hA16, als2, ald2, offsets, edgeSW,
                                                       b2, hB16, N);
  // layer 3: [N,128] @ [128,64], H=1 C=64, no relu, fp32 output
  gemm_mfma_kernel<f16, 64, 1><<<gemmGrid, 256, 0, stream>>>(hB16, WT3, hC16, as3, ad3,
                                                             als3, ald3, N, 128);
  aggregate1_kernel<<<aggGrid, 256, 0, stream>>>(hC16, als3, ald3, offsets, edgeSW,
                                                 b3, (float*)d_out, N);
}